// Round 9
// baseline (223.501 us; speedup 1.0000x reference)
//
#include <hip/hip_runtime.h>

#define BLOCK 256
#define GRID 4096
#define NTHREADS (GRID * BLOCK)   // 1,048,576 threads; 4 rows each = 4,194,304 rows

typedef float  floatx4 __attribute__((ext_vector_type(4)));

__device__ __forceinline__ int argmax8(floatx4 a, floatx4 b) {
    // first-occurrence argmax over 8 (matches jnp.argmax tie-break)
    float m = a.x; int idx = 0;
    if (a.y > m) { m = a.y; idx = 1; }
    if (a.z > m) { m = a.z; idx = 2; }
    if (a.w > m) { m = a.w; idx = 3; }
    if (b.x > m) { m = b.x; idx = 4; }
    if (b.y > m) { m = b.y; idx = 5; }
    if (b.z > m) { m = b.z; idx = 6; }
    if (b.w > m) { m = b.w; idx = 7; }
    return idx;
}

__device__ __forceinline__ int group_of(int c) {
    // classes 0..2 -> 0, 3..5 -> 1, 6..7 -> 2 (branchless)
    return (int)(c >= 3) + (int)(c >= 6);
}

__global__ __launch_bounds__(BLOCK) void path_loss_kernel(
    const float* __restrict__ preds,
    const int* __restrict__ targets,
    float* __restrict__ out,
    int batch) {
    const int tid = blockIdx.x * BLOCK + threadIdx.x;
    unsigned int local = 0;
    const floatx4* pv = reinterpret_cast<const floatx4*>(preds);

    if (batch == 4 * NTHREADS) {
        // fast path (wave-uniform branch): 4 rows/thread, all loads issued
        // up front, non-temporal (nt) — measured −8 µs vs temporal (R8).
        int t[4];
        floatx4 a[4], b[4];
        #pragma unroll
        for (int k = 0; k < 4; ++k)
            t[k] = __builtin_nontemporal_load(&targets[tid + k * NTHREADS]);
        #pragma unroll
        for (int k = 0; k < 4; ++k) {
            const int r = tid + k * NTHREADS;
            a[k] = __builtin_nontemporal_load(&pv[(size_t)r * 2]);
            b[k] = __builtin_nontemporal_load(&pv[(size_t)r * 2 + 1]);
        }
        #pragma unroll
        for (int k = 0; k < 4; ++k)
            local += (unsigned int)(group_of(argmax8(a[k], b[k])) != group_of(t[k]));
    } else {
        for (int r = tid; r < batch; r += NTHREADS) {
            floatx4 a = pv[(size_t)r * 2], b = pv[(size_t)r * 2 + 1];
            int t = targets[r];
            local += (unsigned int)(group_of(argmax8(a, b)) != group_of(t));
        }
    }

    // wave64 reduce
    #pragma unroll
    for (int off = 32; off > 0; off >>= 1)
        local += __shfl_down(local, off, 64);
    __shared__ unsigned int lds[BLOCK / 64];
    const int lane = threadIdx.x & 63;
    const int wave = threadIdx.x >> 6;
    if (lane == 0) lds[wave] = local;
    __syncthreads();
    if (threadIdx.x == 0) {
        unsigned int s = 0;
        #pragma unroll
        for (int i = 0; i < BLOCK / 64; ++i) s += lds[i];
        // one float atomic per block; terms s/2^22 are float-exact, total
        // accumulation error ~1e-5 << 1.3e-2 threshold. No fence needed —
        // kernel-boundary release publishes d_out.
        atomicAdd(out, (float)s * (float)(1.0 / (double)batch));
    }
}

extern "C" void kernel_launch(void* const* d_in, const int* in_sizes, int n_in,
                              void* d_out, int out_size, void* d_ws, size_t ws_size,
                              hipStream_t stream) {
    const float* preds = (const float*)d_in[0];
    const int* targets = (const int*)d_in[1];
    int batch = in_sizes[1];  // 4194304 rows

    hipMemsetAsync(d_out, 0, sizeof(float), stream);
    path_loss_kernel<<<GRID, BLOCK, 0, stream>>>(preds, targets, (float*)d_out, batch);
}

// Round 10
// 190.430 us; speedup vs baseline: 1.1737x; 1.1737x over previous
//
#include <hip/hip_runtime.h>

#define BLOCK 256
#define GRID 4096
#define NTHREADS (GRID * BLOCK)   // 1,048,576 threads; 4 rows each = 4,194,304 rows

typedef float  floatx4 __attribute__((ext_vector_type(4)));

__device__ __forceinline__ int argmax8(floatx4 a, floatx4 b) {
    // first-occurrence argmax over 8 (matches jnp.argmax tie-break)
    float m = a.x; int idx = 0;
    if (a.y > m) { m = a.y; idx = 1; }
    if (a.z > m) { m = a.z; idx = 2; }
    if (a.w > m) { m = a.w; idx = 3; }
    if (b.x > m) { m = b.x; idx = 4; }
    if (b.y > m) { m = b.y; idx = 5; }
    if (b.z > m) { m = b.z; idx = 6; }
    if (b.w > m) { m = b.w; idx = 7; }
    return idx;
}

__device__ __forceinline__ int group_of(int c) {
    // classes 0..2 -> 0, 3..5 -> 1, 6..7 -> 2 (branchless)
    return (int)(c >= 3) + (int)(c >= 6);
}

__global__ __launch_bounds__(BLOCK) void path_loss_partial(
    const float* __restrict__ preds,
    const int* __restrict__ targets,
    unsigned int* __restrict__ partial,
    int batch) {
    const int tid = blockIdx.x * BLOCK + threadIdx.x;
    unsigned int local = 0;
    const floatx4* pv = reinterpret_cast<const floatx4*>(preds);

    if (batch == 4 * NTHREADS) {
        // fast path (wave-uniform branch): 4 rows/thread, all loads issued
        // up front, non-temporal (nt) — measured −8 µs vs temporal (R8).
        floatx4 a[4], b[4];
        int t[4];
        #pragma unroll
        for (int k = 0; k < 4; ++k) {
            const int r = tid + k * NTHREADS;
            a[k] = __builtin_nontemporal_load(&pv[(size_t)r * 2]);
            b[k] = __builtin_nontemporal_load(&pv[(size_t)r * 2 + 1]);
        }
        #pragma unroll
        for (int k = 0; k < 4; ++k)
            t[k] = __builtin_nontemporal_load(&targets[tid + k * NTHREADS]);
        #pragma unroll
        for (int k = 0; k < 4; ++k)
            local += (unsigned int)(group_of(argmax8(a[k], b[k])) != group_of(t[k]));
    } else {
        for (int r = tid; r < batch; r += NTHREADS) {
            floatx4 a = pv[(size_t)r * 2], b = pv[(size_t)r * 2 + 1];
            int t = targets[r];
            local += (unsigned int)(group_of(argmax8(a, b)) != group_of(t));
        }
    }

    // wave64 reduce
    #pragma unroll
    for (int off = 32; off > 0; off >>= 1)
        local += __shfl_down(local, off, 64);
    __shared__ unsigned int lds[BLOCK / 64];
    const int lane = threadIdx.x & 63;
    const int wave = threadIdx.x >> 6;
    if (lane == 0) lds[wave] = local;
    __syncthreads();
    if (threadIdx.x == 0) {
        unsigned int s = 0;
        #pragma unroll
        for (int i = 0; i < BLOCK / 64; ++i) s += lds[i];
        partial[blockIdx.x] = s;   // plain store — no atomics, no fence, no init needed
    }
}

__global__ __launch_bounds__(1024) void path_loss_final(
    const unsigned int* __restrict__ partial,
    float* __restrict__ out,
    int batch) {
    unsigned int local = 0;
    for (int i = threadIdx.x; i < GRID; i += 1024)
        local += partial[i];
    #pragma unroll
    for (int off = 32; off > 0; off >>= 1)
        local += __shfl_down(local, off, 64);
    __shared__ unsigned int lds[16];
    const int lane = threadIdx.x & 63;
    const int wave = threadIdx.x >> 6;
    if (lane == 0) lds[wave] = local;
    __syncthreads();
    if (threadIdx.x == 0) {
        unsigned int total = 0;
        #pragma unroll
        for (int i = 0; i < 16; ++i) total += lds[i];
        out[0] = (float)((double)total / (double)batch);
    }
}

extern "C" void kernel_launch(void* const* d_in, const int* in_sizes, int n_in,
                              void* d_out, int out_size, void* d_ws, size_t ws_size,
                              hipStream_t stream) {
    const float* preds = (const float*)d_in[0];
    const int* targets = (const int*)d_in[1];
    int batch = in_sizes[1];  // 4194304 rows
    unsigned int* partial = (unsigned int*)d_ws;

    path_loss_partial<<<GRID, BLOCK, 0, stream>>>(preds, targets, partial, batch);
    path_loss_final<<<1, 1024, 0, stream>>>(partial, (float*)d_out, batch);
}